// Round 1
// baseline (249.203 us; speedup 1.0000x reference)
//
#include <hip/hip_runtime.h>
#include <hip/hip_bf16.h>

typedef short s8v __attribute__((ext_vector_type(8)));   // 8 bf16 (4 VGPRs) MFMA A/B frag
typedef float f4v __attribute__((ext_vector_type(4)));   // 4 fp32 MFMA C/D frag

#define LDS_PITCH 136  // 128 + 8 ushorts: breaks pow2 stride, keeps 16B alignment

__device__ __forceinline__ unsigned int bfround(float f) {
    unsigned int x = __float_as_uint(f);
    return (x + 0x7fffu + ((x >> 16) & 1u)) >> 16;  // RNE fp32->bf16
}
__device__ __forceinline__ unsigned int pack2(float lo, float hi) {
    return bfround(lo) | (bfround(hi) << 16);
}

// P[N,128] (bf16) = feat[N,128] @ W1[whalf:whalf+128, 0:128] (+ bias)
__global__ __launch_bounds__(256) void proj_kernel(
    const float* __restrict__ feat, const float* __restrict__ W1,
    const float* __restrict__ bias, int whalf,
    unsigned short* __restrict__ P, int nrb)
{
    __shared__ __align__(16) unsigned short Alds[16 * LDS_PITCH];
    const int tid  = threadIdx.x;
    const int lane = tid & 63;
    const int w    = tid >> 6;       // wave 0..3
    const int m    = lane & 15;      // M (A) / N (B) index within tile
    const int q    = lane >> 4;      // quad: selects 8-chunk of K

    // One-time: cache B fragments for this wave's 2 column-tiles (ct=2w,2w+1).
    // B[k][n] with n = ct*16 + m, k = c*32 + q*8 + j.  W is 64KB, L2-hot.
    s8v bfrag[2][4];
    float bias_v[2];
    for (int t = 0; t < 2; ++t) {
        int col = (2 * w + t) * 16 + m;
        for (int c = 0; c < 4; ++c) {
            s8v bf;
            #pragma unroll
            for (int j = 0; j < 8; ++j) {
                int k = c * 32 + q * 8 + j;
                bf[j] = (short)bfround(W1[(whalf + k) * 128 + col]);
            }
            bfrag[t][c] = bf;
        }
        bias_v[t] = bias ? bias[col] : 0.0f;
    }

    for (int rb = blockIdx.x; rb < nrb; rb += gridDim.x) {
        __syncthreads();  // protect LDS from previous iteration's readers
        // Stage 16x128 fp32 A-tile -> bf16 LDS (coalesced float2 loads)
        const float2* frow = (const float2*)feat + (size_t)rb * 16 * 64;
        #pragma unroll
        for (int p = 0; p < 4; ++p) {
            int u = tid + 256 * p;
            int row = u >> 6, pr = u & 63;
            float2 v = frow[row * 64 + pr];
            *(unsigned int*)&Alds[row * LDS_PITCH + pr * 2] = pack2(v.x, v.y);
        }
        __syncthreads();

        f4v acc[2];
        #pragma unroll
        for (int t = 0; t < 2; ++t)
            acc[t] = (f4v){bias_v[t], bias_v[t], bias_v[t], bias_v[t]};

        #pragma unroll
        for (int c = 0; c < 4; ++c) {
            // A[m][k = c*32 + q*8 + j]: one 16B LDS read, 2-way conflict (free)
            s8v af = *(const s8v*)&Alds[m * LDS_PITCH + c * 32 + q * 8];
            acc[0] = __builtin_amdgcn_mfma_f32_16x16x32_bf16(af, bfrag[0][c], acc[0], 0, 0, 0);
            acc[1] = __builtin_amdgcn_mfma_f32_16x16x32_bf16(af, bfrag[1][c], acc[1], 0, 0, 0);
        }

        // C/D layout: col = lane&15, row = (lane>>4)*4 + reg  [m89/m91 verified]
        #pragma unroll
        for (int t = 0; t < 2; ++t) {
            int col = (2 * w + t) * 16 + m;
            #pragma unroll
            for (int r = 0; r < 4; ++r) {
                int row = rb * 16 + q * 4 + r;
                P[(size_t)row * 128 + col] = (unsigned short)bfround(acc[t][r]);
            }
        }
    }
}

// out[e] = relu(Pu[src[e]] + Pm[dst[e]]) . W2 + b2   (b1 already folded into Pm)
// One wave per 4 consecutive edges; lane l holds dims {2l, 2l+1}.
__global__ __launch_bounds__(256) void edge_kernel(
    const int* __restrict__ src, const int* __restrict__ dst,
    const unsigned int* __restrict__ Pu, const unsigned int* __restrict__ Pm,
    const float* __restrict__ W2, const float* __restrict__ b2,
    float* __restrict__ out)
{
    const int tid  = threadIdx.x;
    const int lane = tid & 63;
    const int w    = tid >> 6;
    const int e0   = blockIdx.x * 16 + w * 4;

    const float w2a = W2[2 * lane];
    const float w2b = W2[2 * lane + 1];

    float acc[4];
    #pragma unroll
    for (int i = 0; i < 4; ++i) {
        int e = e0 + i;
        int s = src[e], d = dst[e];
        unsigned int pu = Pu[s * 64 + lane];   // packed bf16 pair, coalesced 256B/wave
        unsigned int pm = Pm[d * 64 + lane];
        float a0 = __uint_as_float(pu << 16)          + __uint_as_float(pm << 16);
        float a1 = __uint_as_float(pu & 0xffff0000u)  + __uint_as_float(pm & 0xffff0000u);
        a0 = fmaxf(a0, 0.0f);
        a1 = fmaxf(a1, 0.0f);
        acc[i] = a0 * w2a + a1 * w2b;
    }

    // butterfly reduce all 4 edges (64 lanes each)
    #pragma unroll
    for (int off = 32; off; off >>= 1) {
        #pragma unroll
        for (int i = 0; i < 4; ++i)
            acc[i] += __shfl_xor(acc[i], off, 64);
    }

    if (lane == 0) {
        float bb = b2[0];
        *(float4*)(out + e0) = make_float4(acc[0] + bb, acc[1] + bb, acc[2] + bb, acc[3] + bb);
    }
}

extern "C" void kernel_launch(void* const* d_in, const int* in_sizes, int n_in,
                              void* d_out, int out_size, void* d_ws, size_t ws_size,
                              hipStream_t stream) {
    const float* userf  = (const float*)d_in[0];
    const float* movief = (const float*)d_in[1];
    const int*   eidx   = (const int*)d_in[2];
    const float* W1     = (const float*)d_in[3];
    const float* b1     = (const float*)d_in[4];
    const float* W2     = (const float*)d_in[5];
    const float* b2     = (const float*)d_in[6];
    float* out = (float*)d_out;

    const int NU = in_sizes[0] / 128;   // 100000
    const int NM = in_sizes[1] / 128;   // 100000
    const int E  = in_sizes[2] / 2;     // 1000000

    unsigned short* Pu = (unsigned short*)d_ws;
    unsigned short* Pm = Pu + (size_t)NU * 128;   // 25.6 MB each, 51.2 MB total

    proj_kernel<<<640, 256, 0, stream>>>(userf,  W1, nullptr, 0,   Pu, NU / 16);
    proj_kernel<<<640, 256, 0, stream>>>(movief, W1, b1,      128, Pm, NM / 16);
    edge_kernel<<<E / 16, 256, 0, stream>>>(eidx, eidx + E,
                                            (const unsigned int*)Pu, (const unsigned int*)Pm,
                                            W2, b2, out);
}